// Round 3
// baseline (192.057 us; speedup 1.0000x reference)
//
#include <hip/hip_runtime.h>

typedef unsigned short u16;
typedef unsigned int   u32;

#define T_TOK 4096
#define D_DIM 1024
#define H_DIM 512
#define E_NUM 8
#define NP1   5120        // padded rows per pass (buckets padded to 128)
#define MAXP  5120

typedef __bf16 bf16x8 __attribute__((ext_vector_type(8)));
typedef float  f32x4  __attribute__((ext_vector_type(4)));

__device__ __forceinline__ u16 f2bf(float f) {
    return __builtin_bit_cast(u16, (__bf16)f);
}
__device__ __forceinline__ u32 pk2(float a, float b) {
    return (u32)f2bf(a) | ((u32)f2bf(b) << 16);
}
__device__ __forceinline__ float bf2f(u32 lo16) {
    return __builtin_bit_cast(float, lo16 << 16);
}

// async 16B global->LDS; per-lane gaddr, wave-uniform LDS base (data lands at base+lane*16)
__device__ __forceinline__ void gll16(const void* g, void* l) {
    __builtin_amdgcn_global_load_lds((const __attribute__((address_space(1))) void*)g,
                                     (__attribute__((address_space(3))) void*)l, 16, 0, 0);
}

// frag read with XOR de-swizzle: tile [128][64] u16, slot = seg ^ (row&7)
#define LDFX(arr, r, ko) __builtin_bit_cast(bf16x8, \
    *(const uint4*)(&arr[r][((((ko) >> 3) ^ ((r) & 7)) << 3)]))
#define MFMA(a, b, c) __builtin_amdgcn_mfma_f32_16x16x32_bf16(a, b, c, 0, 0, 0)

// ---------- fused front: router + conv(w_in) + conv(w_out) + init(e0/e1) ----------
// blocks [0,256)     : router (16 tokens each) + per-block histogram -> blk_hist[bid][16]
// blocks [256,4352)  : w_in fp32 -> bf16
// blocks [4352,6400) : w_out fp32 -> bf16
// blocks [6400,6410) : e0/e1 = -1
__global__ __launch_bounds__(256) void fused_front(
    const float* __restrict__ x, const float* __restrict__ wr,
    const float* __restrict__ w_in, const float* __restrict__ w_out,
    float* __restrict__ logits_out, int* __restrict__ top_e, float* __restrict__ top_g,
    u16* __restrict__ xb, u16* __restrict__ wib, u16* __restrict__ wob,
    int* __restrict__ e_init, int* __restrict__ blk_hist)
{
    const int bid = blockIdx.x;
    const int tid = threadIdx.x;

    if (bid >= 256) {
        const int b2 = bid - 256;
        if (b2 < 4096) {                               // conv w_in: 8 els/thread
            const size_t i = (size_t)b2 * 256 + tid;
            const float4 a = *(const float4*)(w_in + i * 8);
            const float4 b = *(const float4*)(w_in + i * 8 + 4);
            uint4 o;
            o.x = pk2(a.x, a.y); o.y = pk2(a.z, a.w);
            o.z = pk2(b.x, b.y); o.w = pk2(b.z, b.w);
            *(uint4*)(wib + i * 8) = o;
        } else if (b2 < 6144) {                        // conv w_out
            const size_t i = (size_t)(b2 - 4096) * 256 + tid;
            const float4 a = *(const float4*)(w_out + i * 8);
            const float4 b = *(const float4*)(w_out + i * 8 + 4);
            uint4 o;
            o.x = pk2(a.x, a.y); o.y = pk2(a.z, a.w);
            o.z = pk2(b.x, b.y); o.w = pk2(b.z, b.w);
            *(uint4*)(wob + i * 8) = o;
        } else {                                       // init e0..e1 contiguous: -1
            ((int4*)e_init)[(b2 - 6144) * 256 + tid] = make_int4(-1, -1, -1, -1);
        }
        return;
    }

    // ---- router block (bid in [0,256)) ----
    __shared__ float wrL[E_NUM][1024];
    __shared__ int   bh[16];
    if (tid < 16) bh[tid] = 0;
    #pragma unroll
    for (int i = 0; i < 8; ++i) {
        const int idx = (i * 256 + tid) * 4;
        *(float4*)&wrL[0][idx] = *(const float4*)(wr + idx);
    }
    __syncthreads();

    const int lane = tid & 63;
    const int wv   = tid >> 6;
    const int t0   = bid * 16 + wv * 4;

    for (int tt = 0; tt < 4; ++tt) {
        const int t = t0 + tt;
        const float* xr = x + ((size_t)t << 10);
        float4 xv[4];
        #pragma unroll
        for (int j = 0; j < 4; ++j)
            xv[j] = *(const float4*)(xr + j * 256 + lane * 4);

        #pragma unroll
        for (int j = 0; j < 4; ++j) {
            uint2 p;
            p.x = pk2(xv[j].x, xv[j].y);
            p.y = pk2(xv[j].z, xv[j].w);
            *(uint2*)(xb + ((size_t)t << 10) + j * 256 + lane * 4) = p;
        }

        float acc[E_NUM];
        #pragma unroll
        for (int e = 0; e < E_NUM; ++e) acc[e] = 0.f;
        #pragma unroll
        for (int j = 0; j < 4; ++j) {
            #pragma unroll
            for (int e = 0; e < E_NUM; ++e) {
                const float4 w4 = *(const float4*)&wrL[e][j * 256 + lane * 4];
                acc[e] += xv[j].x * w4.x + xv[j].y * w4.y + xv[j].z * w4.z + xv[j].w * w4.w;
            }
        }
        #pragma unroll
        for (int off = 32; off >= 1; off >>= 1) {
            #pragma unroll
            for (int e = 0; e < E_NUM; ++e)
                acc[e] += __shfl_xor(acc[e], off);
        }
        if (lane == 0) {
            #pragma unroll
            for (int e = 0; e < E_NUM; ++e)
                logits_out[t * E_NUM + e] = acc[e];
            int i0 = 0; float v0 = acc[0];
            #pragma unroll
            for (int e = 1; e < E_NUM; ++e) { if (acc[e] > v0) { v0 = acc[e]; i0 = e; } }
            int i1 = (i0 == 0) ? 1 : 0; float v1 = acc[i1];
            #pragma unroll
            for (int e = 0; e < E_NUM; ++e) { if (e != i0 && e != i1 && acc[e] > v1) { v1 = acc[e]; i1 = e; } }
            const float ed = __expf(v1 - v0);
            const float g0 = 1.f / (1.f + ed);
            top_e[2 * t]     = i0;  top_e[2 * t + 1] = i1;
            top_g[2 * t]     = g0;  top_g[2 * t + 1] = 1.f - g0;
            atomicAdd(&bh[2 * i0],     1);
            atomicAdd(&bh[2 * i1 + 1], 1);
        }
    }
    __syncthreads();
    if (tid < 16) blk_hist[bid * 16 + tid] = bh[tid];
}

// ---------- prep: parallel hist-reduce + offsets + g1/g2 tile table + scatter ----------
// ws_i: [99] ntiles, table @512 (<=96): (e<<16)|rb_global  (rb_global = k*NP1 + local)
__global__ __launch_bounds__(1024) void prep_kernel(
    const int* __restrict__ top_e, int* __restrict__ ws_i,
    int* __restrict__ e0, int* __restrict__ e1, const int* __restrict__ blk_hist)
{
    __shared__ int hist[16];
    __shared__ int cur[16];
    const int tid = threadIdx.x;
    if (tid < 16) hist[tid] = 0;
    __syncthreads();

    // reduce 256x16 per-block histograms: flat index i contributes to bucket i&15;
    // thread tid covers {tid, tid+1024, tid+2048, tid+3072} -> fixed bucket tid&15
    int part = 0;
    #pragma unroll
    for (int j = 0; j < 4; ++j) part += blk_hist[j * 1024 + tid];
    part += __shfl_xor(part, 16);
    part += __shfl_xor(part, 32);
    if ((tid & 63) < 16) atomicAdd(&hist[tid & 15], part);
    __syncthreads();

    if (tid == 0) {
        int off_[16];
        int s0 = 0, s1 = 0;
        for (int e = 0; e < E_NUM; ++e) {
            off_[2 * e]     = s0; s0 += (hist[2 * e]     + 127) & ~127;
            off_[2 * e + 1] = s1; s1 += (hist[2 * e + 1] + 127) & ~127;
        }
        int nt1 = 0;
        for (int e = 0; e < E_NUM; ++e) {
            for (int k = 0; k < 2; ++k) {
                const int b  = 2 * e + k;
                const int pc = (hist[b] + 127) & ~127;
                cur[b] = off_[b];
                for (int j = 0; j < pc / 128; ++j) {
                    const int rl = off_[b] + j * 128;
                    if (nt1 < 96) ws_i[512 + nt1++] = (e << 16) | (k * NP1 + rl);
                }
            }
        }
        ws_i[99] = nt1;
    }
    __syncthreads();

    // scatter: 8192 entries, 8 per thread, batched int4 loads
    const int4* t4 = (const int4*)top_e;
    const int4 a = t4[2 * tid];
    const int4 b = t4[2 * tid + 1];
    const int v[8] = {a.x, a.y, a.z, a.w, b.x, b.y, b.z, b.w};
    #pragma unroll
    for (int j = 0; j < 8; ++j) {
        const int i  = tid * 8 + j;          // i&1 == j&1
        const int bk = 2 * (v[j] & 7) + (j & 1);
        const int pos = atomicAdd(&cur[bk], 1);
        ((j & 1) ? e1 : e0)[pos] = i;
    }
}

// ---------- g1: 128x128 tile, async bf16 staging, act = swiglu(xb @ wib[e]^T) ----------
// launch_bounds (256,4): 33.8KB LDS -> 4 blocks/CU fit; VGPR 72 <= 128 cap.
// All 640 blocks co-resident (1024 slots) -> no tail, 2x latency-hiding waves.
__global__ __launch_bounds__(256, 4) void g1_a(
    const u16* __restrict__ xb, const u16* __restrict__ wib,
    const int* __restrict__ ws_i, const int* __restrict__ e0,
    const int* __restrict__ e1, u16* __restrict__ act)
{
    const int nt = ws_i[99];
    if ((int)blockIdx.y >= nt) return;
    const int tile = ws_i[512 + blockIdx.y];
    const int e  = tile >> 16;
    const int rb = tile & 0xFFFF;        // global padded row base (mult 128)
    const int nc = blockIdx.x;           // h-col block 0..7

    __shared__ __align__(16) u16 xs[128][64];
    __shared__ __align__(16) u16 wt[128][64];
    __shared__ int tokL[128];

    const int tid = threadIdx.x;
    if (tid < 128) {
        const int ent = (rb >= NP1) ? e1[rb - NP1 + tid] : e0[rb + tid];
        tokL[tid] = (ent < 0) ? 0 : (ent >> 1);
    }
    __syncthreads();

    const int wid = tid >> 6, ln = tid & 63, qd = ln >> 4, lm = ln & 15;
    const int wrh = wid >> 1, wch = wid & 1;

    // per-lane gather setup: 4 xs rows + 4 wt rows (8 lanes/row, XOR-swizzled segs)
    const u16* xsrc[4];
    const u16* wsrc[4];
    const u16* wbase = wib + ((size_t)e << 20);
    #pragma unroll
    for (int j = 0; j < 4; ++j) {
        const int r  = wid * 32 + j * 8 + (ln >> 3);
        const int sg = (ln & 7) ^ (r & 7);
        xsrc[j] = xb + ((size_t)tokL[r] << 10) + (sg << 3);
        const int h = r >> 6, r2 = r & 63;
        const int wrow = (r2 < 32) ? (nc * 64 + h * 32 + r2)
                                   : (512 + nc * 64 + h * 32 + (r2 - 32));
        wsrc[j] = wbase + ((size_t)wrow << 10) + (sg << 3);
    }

    f32x4 acc[4][4];
    #pragma unroll
    for (int i = 0; i < 4; ++i)
        #pragma unroll
        for (int j = 0; j < 4; ++j) acc[i][j] = (f32x4){0.f,0.f,0.f,0.f};

    for (int k0 = 0; k0 < 1024; k0 += 64) {
        #pragma unroll
        for (int j = 0; j < 4; ++j) {
            gll16(xsrc[j] + k0, &xs[wid * 32 + j * 8][0]);
            gll16(wsrc[j] + k0, &wt[wid * 32 + j * 8][0]);
        }
        __syncthreads();                          // drains vmcnt; tiles ready
        #pragma unroll
        for (int ki = 0; ki < 2; ++ki) {
            const int ko = ki * 32 + (qd << 3);
            bf16x8 aF[4], bF[4];
            #pragma unroll
            for (int i = 0; i < 4; ++i) aF[i] = LDFX(xs, wrh * 64 + i * 16 + lm, ko);
            #pragma unroll
            for (int j = 0; j < 4; ++j) bF[j] = LDFX(wt, wch * 64 + j * 16 + lm, ko);
            #pragma unroll
            for (int i = 0; i < 4; ++i)
                #pragma unroll
                for (int j = 0; j < 4; ++j)
                    acc[i][j] = MFMA(aF[i], bF[j], acc[i][j]);
        }
        __syncthreads();                          // frag reads done before overwrite
    }

    // SwiGLU in-register: j (a-half) pairs with j+2 (b-half), same lane
    #pragma unroll
    for (int i = 0; i < 4; ++i) {
        #pragma unroll
        for (int j = 0; j < 2; ++j) {
            #pragma unroll
            for (int r = 0; r < 4; ++r) {
                const float a = acc[i][j][r], b = acc[i][j + 2][r];
                const float v = b * a / (1.f + __expf(-a));
                const int row  = wrh * 64 + i * 16 + (qd << 2) + r;
                const int hcol = nc * 64 + wch * 32 + j * 16 + lm;
                act[((size_t)(rb + row) << 9) + hcol] = f2bf(v);
            }
        }
    }
}

// ---------- g2: single pass; gated partial -> y[ent][1024] bf16, plain stores ----------
__global__ __launch_bounds__(256, 4) void g2_a(
    const u16* __restrict__ act, const u16* __restrict__ wob,
    const int* __restrict__ ws_i, const int* __restrict__ e0,
    const int* __restrict__ e1, const float* __restrict__ top_g,
    u16* __restrict__ y)
{
    const int nt = ws_i[99];
    if ((int)blockIdx.y >= nt) return;
    const int tile = ws_i[512 + blockIdx.y];
    const int e  = tile >> 16;
    const int rb = tile & 0xFFFF;        // global padded act row base
    const int dc = blockIdx.x;           // out-col block 0..7

    __shared__ __align__(16) u16 as_[128][64];
    __shared__ __align__(16) u16 wt2[128][64];
    __shared__ int   entL[128];
    __shared__ float gateL[128];

    const int tid = threadIdx.x;
    if (tid < 128) {
        const int ent = (rb >= NP1) ? e1[rb - NP1 + tid] : e0[rb + tid];
        entL[tid]  = ent;
        gateL[tid] = (ent < 0) ? 0.f : top_g[ent];
    }
    __syncthreads();

    const int wid = tid >> 6, ln = tid & 63, qd = ln >> 4, lm = ln & 15;
    const int wrh = wid >> 1, wch = wid & 1;

    const u16* asrc[4];
    const u16* wsrc[4];
    const u16* wbase = wob + ((size_t)e << 19);
    #pragma unroll
    for (int j = 0; j < 4; ++j) {
        const int r  = wid * 32 + j * 8 + (ln >> 3);
        const int sg = (ln & 7) ^ (r & 7);
        asrc[j] = act + ((size_t)(rb + r) << 9) + (sg << 3);
        wsrc[j] = wbase + ((size_t)((dc << 7) + r) << 9) + (sg << 3);
    }

    f32x4 acc[4][4];
    #pragma unroll
    for (int i = 0; i < 4; ++i)
        #pragma unroll
        for (int j = 0; j < 4; ++j) acc[i][j] = (f32x4){0.f,0.f,0.f,0.f};

    for (int k0 = 0; k0 < 512; k0 += 64) {
        #pragma unroll
        for (int j = 0; j < 4; ++j) {
            gll16(asrc[j] + k0, &as_[wid * 32 + j * 8][0]);
            gll16(wsrc[j] + k0, &wt2[wid * 32 + j * 8][0]);
        }
        __syncthreads();
        #pragma unroll
        for (int ki = 0; ki < 2; ++ki) {
            const int ko = ki * 32 + (qd << 3);
            bf16x8 aF[4], bF[4];
            #pragma unroll
            for (int i = 0; i < 4; ++i) aF[i] = LDFX(as_, wrh * 64 + i * 16 + lm, ko);
            #pragma unroll
            for (int j = 0; j < 4; ++j) bF[j] = LDFX(wt2, wch * 64 + j * 16 + lm, ko);
            #pragma unroll
            for (int i = 0; i < 4; ++i)
                #pragma unroll
                for (int j = 0; j < 4; ++j)
                    acc[i][j] = MFMA(aF[i], bF[j], acc[i][j]);
        }
        __syncthreads();
    }

    #pragma unroll
    for (int i = 0; i < 4; ++i) {
        #pragma unroll
        for (int j = 0; j < 4; ++j) {
            #pragma unroll
            for (int r = 0; r < 4; ++r) {
                const int row = wrh * 64 + i * 16 + (qd << 2) + r;
                const int ent = entL[row];
                if (ent >= 0) {
                    const int col = (dc << 7) + wch * 64 + j * 16 + lm;
                    y[((size_t)ent << 10) + col] = f2bf(gateL[row] * acc[i][j][r]);
                }
            }
        }
    }
}

// ---------- combine: out[t] = f32(y[2t]) + f32(y[2t+1]) ----------
__global__ __launch_bounds__(256) void combine_kernel(
    const u16* __restrict__ y, float* __restrict__ out)
{
    const int idx = blockIdx.x * 256 + threadIdx.x;   // 524288 threads, 8 els each
    const int t = idx >> 7;
    const int c = (idx & 127) << 3;
    const uint4 a = *(const uint4*)(y + ((size_t)(2 * t)     << 10) + c);
    const uint4 b = *(const uint4*)(y + ((size_t)(2 * t + 1) << 10) + c);
    float4 o0, o1;
    o0.x = bf2f(a.x & 0xFFFFu) + bf2f(b.x & 0xFFFFu);
    o0.y = bf2f(a.x >> 16)     + bf2f(b.x >> 16);
    o0.z = bf2f(a.y & 0xFFFFu) + bf2f(b.y & 0xFFFFu);
    o0.w = bf2f(a.y >> 16)     + bf2f(b.y >> 16);
    o1.x = bf2f(a.z & 0xFFFFu) + bf2f(b.z & 0xFFFFu);
    o1.y = bf2f(a.z >> 16)     + bf2f(b.z >> 16);
    o1.z = bf2f(a.w & 0xFFFFu) + bf2f(b.w & 0xFFFFu);
    o1.w = bf2f(a.w >> 16)     + bf2f(b.w >> 16);
    float* po = out + ((size_t)t << 10) + c;
    *(float4*)po       = o0;
    *(float4*)(po + 4) = o1;
}

extern "C" void kernel_launch(void* const* d_in, const int* in_sizes, int n_in,
                              void* d_out, int out_size, void* d_ws, size_t ws_size,
                              hipStream_t stream)
{
    (void)in_sizes; (void)n_in; (void)out_size; (void)ws_size;
    const float* x     = (const float*)d_in[0];   // [4096,1024] fp32
    const float* wr    = (const float*)d_in[1];   // [8,1024]
    const float* w_in  = (const float*)d_in[2];   // [8,1024,1024]
    const float* w_out = (const float*)d_in[3];   // [8,1024,512]
    float* out = (float*)d_out;                   // [4096*1024] out ++ [4096*8] logits

    char* ws = (char*)d_ws;                           // peak 42.1 MB (<= 43 MB proven)
    int*   ws_i     = (int*)ws;                       //  8 KB control + tables
    int*   e0       = (int*)(ws + 8192);              // 20 KB entries k=0
    int*   e1       = (int*)(ws + 28672);             // 20 KB entries k=1 (contiguous w/ e0)
    int*   top_e    = (int*)(ws + 49152);             // 32 KB
    float* top_g    = (float*)(ws + 81920);           // 32 KB
    int*   blk_hist = (int*)(ws + 114688);            // 16 KB per-router-block hist
    u16*   act      = (u16*)(ws + 147456);            // 10240*512*2 = 10.5 MB
    u16*   xb       = (u16*)(ws + 10633216);          //  8 MB bf16 x (dead after g1)
    u16*   wib      = (u16*)(ws + 19021824);          // 16 MB bf16 w_in (dead after g1)
    u16*   y        = (u16*)(ws + 10633216);          // 16.8 MB bf16 partials, over dead xb+wib
    u16*   wob      = (u16*)(ws + 35799040);          //  8 MB bf16 w_out

    fused_front<<<6410, 256, 0, stream>>>(x, wr, w_in, w_out,
                                          out + (size_t)T_TOK * D_DIM,
                                          top_e, top_g, xb, wib, wob,
                                          e0, blk_hist);
    prep_kernel<<<1, 1024, 0, stream>>>(top_e, ws_i, e0, e1, blk_hist);
    g1_a<<<dim3(8, 80), 256, 0, stream>>>(xb, wib, ws_i, e0, e1, act);
    g2_a<<<dim3(8, 80), 256, 0, stream>>>(act, wob, ws_i, e0, e1, top_g, y);
    combine_kernel<<<2048, 256, 0, stream>>>(y, out);
}

// Round 4
// 164.882 us; speedup vs baseline: 1.1648x; 1.1648x over previous
//
#include <hip/hip_runtime.h>

typedef unsigned short u16;
typedef unsigned int   u32;

#define T_TOK 4096
#define D_DIM 1024
#define H_DIM 512
#define E_NUM 8
#define NP1   5120        // padded rows per pass (buckets padded to 128)
#define MAXP  5120

typedef __bf16 bf16x8 __attribute__((ext_vector_type(8)));
typedef float  f32x4  __attribute__((ext_vector_type(4)));

__device__ __forceinline__ u16 f2bf(float f) {
    return __builtin_bit_cast(u16, (__bf16)f);
}
__device__ __forceinline__ u32 pk2(float a, float b) {
    return (u32)f2bf(a) | ((u32)f2bf(b) << 16);
}
__device__ __forceinline__ float bf2f(u32 lo16) {
    return __builtin_bit_cast(float, lo16 << 16);
}

// async 16B global->LDS; per-lane gaddr, wave-uniform LDS base (data lands at base+lane*16)
__device__ __forceinline__ void gll16(const void* g, void* l) {
    __builtin_amdgcn_global_load_lds((const __attribute__((address_space(1))) void*)g,
                                     (__attribute__((address_space(3))) void*)l, 16, 0, 0);
}

// frag read with XOR de-swizzle: tile [128][64] u16, slot = seg ^ (row&7)
#define LDFX(arr, r, ko) __builtin_bit_cast(bf16x8, \
    *(const uint4*)(&arr[r][((((ko) >> 3) ^ ((r) & 7)) << 3)]))
#define MFMA(a, b, c) __builtin_amdgcn_mfma_f32_16x16x32_bf16(a, b, c, 0, 0, 0)

// ---------- fused front: router + conv(w_in) + conv(w_out) + init(e0/e1) ----------
// blocks [0,256)     : router (16 tokens each) + per-block histogram -> blk_hist[bid][16]
// blocks [256,4352)  : w_in fp32 -> bf16
// blocks [4352,6400) : w_out fp32 -> bf16
// blocks [6400,6410) : e0/e1 = -1
__global__ __launch_bounds__(256) void fused_front(
    const float* __restrict__ x, const float* __restrict__ wr,
    const float* __restrict__ w_in, const float* __restrict__ w_out,
    float* __restrict__ logits_out, int* __restrict__ top_e, float* __restrict__ top_g,
    u16* __restrict__ xb, u16* __restrict__ wib, u16* __restrict__ wob,
    int* __restrict__ e_init, int* __restrict__ blk_hist)
{
    const int bid = blockIdx.x;
    const int tid = threadIdx.x;

    if (bid >= 256) {
        const int b2 = bid - 256;
        if (b2 < 4096) {                               // conv w_in: 8 els/thread
            const size_t i = (size_t)b2 * 256 + tid;
            const float4 a = *(const float4*)(w_in + i * 8);
            const float4 b = *(const float4*)(w_in + i * 8 + 4);
            uint4 o;
            o.x = pk2(a.x, a.y); o.y = pk2(a.z, a.w);
            o.z = pk2(b.x, b.y); o.w = pk2(b.z, b.w);
            *(uint4*)(wib + i * 8) = o;
        } else if (b2 < 6144) {                        // conv w_out
            const size_t i = (size_t)(b2 - 4096) * 256 + tid;
            const float4 a = *(const float4*)(w_out + i * 8);
            const float4 b = *(const float4*)(w_out + i * 8 + 4);
            uint4 o;
            o.x = pk2(a.x, a.y); o.y = pk2(a.z, a.w);
            o.z = pk2(b.x, b.y); o.w = pk2(b.z, b.w);
            *(uint4*)(wob + i * 8) = o;
        } else {                                       // init e0..e1 contiguous: -1
            ((int4*)e_init)[(b2 - 6144) * 256 + tid] = make_int4(-1, -1, -1, -1);
        }
        return;
    }

    // ---- router block (bid in [0,256)) ----
    __shared__ float wrL[E_NUM][1024];
    __shared__ int   bh[16];
    if (tid < 16) bh[tid] = 0;
    #pragma unroll
    for (int i = 0; i < 8; ++i) {
        const int idx = (i * 256 + tid) * 4;
        *(float4*)&wrL[0][idx] = *(const float4*)(wr + idx);
    }
    __syncthreads();

    const int lane = tid & 63;
    const int wv   = tid >> 6;
    const int t0   = bid * 16 + wv * 4;

    for (int tt = 0; tt < 4; ++tt) {
        const int t = t0 + tt;
        const float* xr = x + ((size_t)t << 10);
        float4 xv[4];
        #pragma unroll
        for (int j = 0; j < 4; ++j)
            xv[j] = *(const float4*)(xr + j * 256 + lane * 4);

        #pragma unroll
        for (int j = 0; j < 4; ++j) {
            uint2 p;
            p.x = pk2(xv[j].x, xv[j].y);
            p.y = pk2(xv[j].z, xv[j].w);
            *(uint2*)(xb + ((size_t)t << 10) + j * 256 + lane * 4) = p;
        }

        float acc[E_NUM];
        #pragma unroll
        for (int e = 0; e < E_NUM; ++e) acc[e] = 0.f;
        #pragma unroll
        for (int j = 0; j < 4; ++j) {
            #pragma unroll
            for (int e = 0; e < E_NUM; ++e) {
                const float4 w4 = *(const float4*)&wrL[e][j * 256 + lane * 4];
                acc[e] += xv[j].x * w4.x + xv[j].y * w4.y + xv[j].z * w4.z + xv[j].w * w4.w;
            }
        }
        #pragma unroll
        for (int off = 32; off >= 1; off >>= 1) {
            #pragma unroll
            for (int e = 0; e < E_NUM; ++e)
                acc[e] += __shfl_xor(acc[e], off);
        }
        if (lane == 0) {
            #pragma unroll
            for (int e = 0; e < E_NUM; ++e)
                logits_out[t * E_NUM + e] = acc[e];
            int i0 = 0; float v0 = acc[0];
            #pragma unroll
            for (int e = 1; e < E_NUM; ++e) { if (acc[e] > v0) { v0 = acc[e]; i0 = e; } }
            int i1 = (i0 == 0) ? 1 : 0; float v1 = acc[i1];
            #pragma unroll
            for (int e = 0; e < E_NUM; ++e) { if (e != i0 && e != i1 && acc[e] > v1) { v1 = acc[e]; i1 = e; } }
            const float ed = __expf(v1 - v0);
            const float g0 = 1.f / (1.f + ed);
            top_e[2 * t]     = i0;  top_e[2 * t + 1] = i1;
            top_g[2 * t]     = g0;  top_g[2 * t + 1] = 1.f - g0;
            atomicAdd(&bh[2 * i0],     1);
            atomicAdd(&bh[2 * i1 + 1], 1);
        }
    }
    __syncthreads();
    if (tid < 16) blk_hist[bid * 16 + tid] = bh[tid];
}

// ---------- prep: parallel hist-reduce + offsets + g1/g2 tile table + scatter ----------
// ws_i: [99] ntiles, table @512 (<=96): (e<<16)|rb_global  (rb_global = k*NP1 + local)
__global__ __launch_bounds__(1024) void prep_kernel(
    const int* __restrict__ top_e, int* __restrict__ ws_i,
    int* __restrict__ e0, int* __restrict__ e1, const int* __restrict__ blk_hist)
{
    __shared__ int hist[16];
    __shared__ int cur[16];
    const int tid = threadIdx.x;
    if (tid < 16) hist[tid] = 0;
    __syncthreads();

    // reduce 256x16 per-block histograms: flat index i contributes to bucket i&15;
    // thread tid covers {tid, tid+1024, tid+2048, tid+3072} -> fixed bucket tid&15
    int part = 0;
    #pragma unroll
    for (int j = 0; j < 4; ++j) part += blk_hist[j * 1024 + tid];
    part += __shfl_xor(part, 16);
    part += __shfl_xor(part, 32);
    if ((tid & 63) < 16) atomicAdd(&hist[tid & 15], part);
    __syncthreads();

    if (tid == 0) {
        int off_[16];
        int s0 = 0, s1 = 0;
        for (int e = 0; e < E_NUM; ++e) {
            off_[2 * e]     = s0; s0 += (hist[2 * e]     + 127) & ~127;
            off_[2 * e + 1] = s1; s1 += (hist[2 * e + 1] + 127) & ~127;
        }
        int nt1 = 0;
        for (int e = 0; e < E_NUM; ++e) {
            for (int k = 0; k < 2; ++k) {
                const int b  = 2 * e + k;
                const int pc = (hist[b] + 127) & ~127;
                cur[b] = off_[b];
                for (int j = 0; j < pc / 128; ++j) {
                    const int rl = off_[b] + j * 128;
                    if (nt1 < 96) ws_i[512 + nt1++] = (e << 16) | (k * NP1 + rl);
                }
            }
        }
        ws_i[99] = nt1;
    }
    __syncthreads();

    // scatter: 8192 entries, 8 per thread, batched int4 loads
    const int4* t4 = (const int4*)top_e;
    const int4 a = t4[2 * tid];
    const int4 b = t4[2 * tid + 1];
    const int v[8] = {a.x, a.y, a.z, a.w, b.x, b.y, b.z, b.w};
    #pragma unroll
    for (int j = 0; j < 8; ++j) {
        const int i  = tid * 8 + j;          // i&1 == j&1
        const int bk = 2 * (v[j] & 7) + (j & 1);
        const int pos = atomicAdd(&cur[bk], 1);
        ((j & 1) ? e1 : e0)[pos] = i;
    }
}

// ---------- g1: 128x128 tile, async bf16 staging, act = swiglu(xb @ wib[e]^T) ----------
// 1D grid 640 = 8 XCD-chunks x 10 tiles x 8 nc. bid%8 ~= XCD, so XCD c owns
// tiles [10c,10c+10) for ALL nc: its expert's wib slice (2MB) + xs rows (2.5MB)
// become L2-resident. launch_bounds (256,2): VGPR 72 + 64 AGPR, 3 blocks/CU actual.
__global__ __launch_bounds__(256, 2) void g1_a(
    const u16* __restrict__ xb, const u16* __restrict__ wib,
    const int* __restrict__ ws_i, const int* __restrict__ e0,
    const int* __restrict__ e1, u16* __restrict__ act)
{
    const int nt  = ws_i[99];
    const int bid = blockIdx.x;
    const int ty  = (bid & 7) * 10 + ((bid >> 3) % 10);  // tile index (XCD-chunked)
    const int nc  = bid / 80;                            // h-col block 0..7
    if (ty >= nt) return;
    const int tile = ws_i[512 + ty];
    const int e  = tile >> 16;
    const int rb = tile & 0xFFFF;        // global padded row base (mult 128)

    __shared__ __align__(16) u16 xs[128][64];
    __shared__ __align__(16) u16 wt[128][64];
    __shared__ int tokL[128];

    const int tid = threadIdx.x;
    if (tid < 128) {
        const int ent = (rb >= NP1) ? e1[rb - NP1 + tid] : e0[rb + tid];
        tokL[tid] = (ent < 0) ? 0 : (ent >> 1);
    }
    __syncthreads();

    const int wid = tid >> 6, ln = tid & 63, qd = ln >> 4, lm = ln & 15;
    const int wrh = wid >> 1, wch = wid & 1;

    // per-lane gather setup: 4 xs rows + 4 wt rows (8 lanes/row, XOR-swizzled segs)
    const u16* xsrc[4];
    const u16* wsrc[4];
    const u16* wbase = wib + ((size_t)e << 20);
    #pragma unroll
    for (int j = 0; j < 4; ++j) {
        const int r  = wid * 32 + j * 8 + (ln >> 3);
        const int sg = (ln & 7) ^ (r & 7);
        xsrc[j] = xb + ((size_t)tokL[r] << 10) + (sg << 3);
        const int h = r >> 6, r2 = r & 63;
        const int wrow = (r2 < 32) ? (nc * 64 + h * 32 + r2)
                                   : (512 + nc * 64 + h * 32 + (r2 - 32));
        wsrc[j] = wbase + ((size_t)wrow << 10) + (sg << 3);
    }

    f32x4 acc[4][4];
    #pragma unroll
    for (int i = 0; i < 4; ++i)
        #pragma unroll
        for (int j = 0; j < 4; ++j) acc[i][j] = (f32x4){0.f,0.f,0.f,0.f};

    for (int k0 = 0; k0 < 1024; k0 += 64) {
        #pragma unroll
        for (int j = 0; j < 4; ++j) {
            gll16(xsrc[j] + k0, &xs[wid * 32 + j * 8][0]);
            gll16(wsrc[j] + k0, &wt[wid * 32 + j * 8][0]);
        }
        __syncthreads();                          // drains vmcnt; tiles ready
        #pragma unroll
        for (int ki = 0; ki < 2; ++ki) {
            const int ko = ki * 32 + (qd << 3);
            bf16x8 aF[4], bF[4];
            #pragma unroll
            for (int i = 0; i < 4; ++i) aF[i] = LDFX(xs, wrh * 64 + i * 16 + lm, ko);
            #pragma unroll
            for (int j = 0; j < 4; ++j) bF[j] = LDFX(wt, wch * 64 + j * 16 + lm, ko);
            #pragma unroll
            for (int i = 0; i < 4; ++i)
                #pragma unroll
                for (int j = 0; j < 4; ++j)
                    acc[i][j] = MFMA(aF[i], bF[j], acc[i][j]);
        }
        __syncthreads();                          // frag reads done before overwrite
    }

    // SwiGLU in-register: j (a-half) pairs with j+2 (b-half), same lane
    #pragma unroll
    for (int i = 0; i < 4; ++i) {
        #pragma unroll
        for (int j = 0; j < 2; ++j) {
            #pragma unroll
            for (int r = 0; r < 4; ++r) {
                const float a = acc[i][j][r], b = acc[i][j + 2][r];
                const float v = b * a / (1.f + __expf(-a));
                const int row  = wrh * 64 + i * 16 + (qd << 2) + r;
                const int hcol = nc * 64 + wch * 32 + j * 16 + lm;
                act[((size_t)(rb + row) << 9) + hcol] = f2bf(v);
            }
        }
    }
}

// ---------- g2: single pass; gated partial -> y[ent][1024] bf16, plain stores ----------
// same XCD-chunked mapping: XCD c re-reads the act rows it wrote in g1 (L2-resident)
__global__ __launch_bounds__(256, 2) void g2_a(
    const u16* __restrict__ act, const u16* __restrict__ wob,
    const int* __restrict__ ws_i, const int* __restrict__ e0,
    const int* __restrict__ e1, const float* __restrict__ top_g,
    u16* __restrict__ y)
{
    const int nt  = ws_i[99];
    const int bid = blockIdx.x;
    const int ty  = (bid & 7) * 10 + ((bid >> 3) % 10);  // tile index (XCD-chunked)
    const int dc  = bid / 80;                            // out-col block 0..7
    if (ty >= nt) return;
    const int tile = ws_i[512 + ty];
    const int e  = tile >> 16;
    const int rb = tile & 0xFFFF;        // global padded act row base

    __shared__ __align__(16) u16 as_[128][64];
    __shared__ __align__(16) u16 wt2[128][64];
    __shared__ int   entL[128];
    __shared__ float gateL[128];

    const int tid = threadIdx.x;
    if (tid < 128) {
        const int ent = (rb >= NP1) ? e1[rb - NP1 + tid] : e0[rb + tid];
        entL[tid]  = ent;
        gateL[tid] = (ent < 0) ? 0.f : top_g[ent];
    }
    __syncthreads();

    const int wid = tid >> 6, ln = tid & 63, qd = ln >> 4, lm = ln & 15;
    const int wrh = wid >> 1, wch = wid & 1;

    const u16* asrc[4];
    const u16* wsrc[4];
    const u16* wbase = wob + ((size_t)e << 19);
    #pragma unroll
    for (int j = 0; j < 4; ++j) {
        const int r  = wid * 32 + j * 8 + (ln >> 3);
        const int sg = (ln & 7) ^ (r & 7);
        asrc[j] = act + ((size_t)(rb + r) << 9) + (sg << 3);
        wsrc[j] = wbase + ((size_t)((dc << 7) + r) << 9) + (sg << 3);
    }

    f32x4 acc[4][4];
    #pragma unroll
    for (int i = 0; i < 4; ++i)
        #pragma unroll
        for (int j = 0; j < 4; ++j) acc[i][j] = (f32x4){0.f,0.f,0.f,0.f};

    for (int k0 = 0; k0 < 512; k0 += 64) {
        #pragma unroll
        for (int j = 0; j < 4; ++j) {
            gll16(asrc[j] + k0, &as_[wid * 32 + j * 8][0]);
            gll16(wsrc[j] + k0, &wt2[wid * 32 + j * 8][0]);
        }
        __syncthreads();
        #pragma unroll
        for (int ki = 0; ki < 2; ++ki) {
            const int ko = ki * 32 + (qd << 3);
            bf16x8 aF[4], bF[4];
            #pragma unroll
            for (int i = 0; i < 4; ++i) aF[i] = LDFX(as_, wrh * 64 + i * 16 + lm, ko);
            #pragma unroll
            for (int j = 0; j < 4; ++j) bF[j] = LDFX(wt2, wch * 64 + j * 16 + lm, ko);
            #pragma unroll
            for (int i = 0; i < 4; ++i)
                #pragma unroll
                for (int j = 0; j < 4; ++j)
                    acc[i][j] = MFMA(aF[i], bF[j], acc[i][j]);
        }
        __syncthreads();
    }

    #pragma unroll
    for (int i = 0; i < 4; ++i) {
        #pragma unroll
        for (int j = 0; j < 4; ++j) {
            #pragma unroll
            for (int r = 0; r < 4; ++r) {
                const int row = wrh * 64 + i * 16 + (qd << 2) + r;
                const int ent = entL[row];
                if (ent >= 0) {
                    const int col = (dc << 7) + wch * 64 + j * 16 + lm;
                    y[((size_t)ent << 10) + col] = f2bf(gateL[row] * acc[i][j][r]);
                }
            }
        }
    }
}

// ---------- combine: out[t] = f32(y[2t]) + f32(y[2t+1]) ----------
__global__ __launch_bounds__(256) void combine_kernel(
    const u16* __restrict__ y, float* __restrict__ out)
{
    const int idx = blockIdx.x * 256 + threadIdx.x;   // 524288 threads, 8 els each
    const int t = idx >> 7;
    const int c = (idx & 127) << 3;
    const uint4 a = *(const uint4*)(y + ((size_t)(2 * t)     << 10) + c);
    const uint4 b = *(const uint4*)(y + ((size_t)(2 * t + 1) << 10) + c);
    float4 o0, o1;
    o0.x = bf2f(a.x & 0xFFFFu) + bf2f(b.x & 0xFFFFu);
    o0.y = bf2f(a.x >> 16)     + bf2f(b.x >> 16);
    o0.z = bf2f(a.y & 0xFFFFu) + bf2f(b.y & 0xFFFFu);
    o0.w = bf2f(a.y >> 16)     + bf2f(b.y >> 16);
    o1.x = bf2f(a.z & 0xFFFFu) + bf2f(b.z & 0xFFFFu);
    o1.y = bf2f(a.z >> 16)     + bf2f(b.z >> 16);
    o1.z = bf2f(a.w & 0xFFFFu) + bf2f(b.w & 0xFFFFu);
    o1.w = bf2f(a.w >> 16)     + bf2f(b.w >> 16);
    float* po = out + ((size_t)t << 10) + c;
    *(float4*)po       = o0;
    *(float4*)(po + 4) = o1;
}

extern "C" void kernel_launch(void* const* d_in, const int* in_sizes, int n_in,
                              void* d_out, int out_size, void* d_ws, size_t ws_size,
                              hipStream_t stream)
{
    (void)in_sizes; (void)n_in; (void)out_size; (void)ws_size;
    const float* x     = (const float*)d_in[0];   // [4096,1024] fp32
    const float* wr    = (const float*)d_in[1];   // [8,1024]
    const float* w_in  = (const float*)d_in[2];   // [8,1024,1024]
    const float* w_out = (const float*)d_in[3];   // [8,1024,512]
    float* out = (float*)d_out;                   // [4096*1024] out ++ [4096*8] logits

    char* ws = (char*)d_ws;                           // peak 42.1 MB (<= 43 MB proven)
    int*   ws_i     = (int*)ws;                       //  8 KB control + tables
    int*   e0       = (int*)(ws + 8192);              // 20 KB entries k=0
    int*   e1       = (int*)(ws + 28672);             // 20 KB entries k=1 (contiguous w/ e0)
    int*   top_e    = (int*)(ws + 49152);             // 32 KB
    float* top_g    = (float*)(ws + 81920);           // 32 KB
    int*   blk_hist = (int*)(ws + 114688);            // 16 KB per-router-block hist
    u16*   act      = (u16*)(ws + 147456);            // 10240*512*2 = 10.5 MB
    u16*   xb       = (u16*)(ws + 10633216);          //  8 MB bf16 x (dead after g1)
    u16*   wib      = (u16*)(ws + 19021824);          // 16 MB bf16 w_in (dead after g1)
    u16*   y        = (u16*)(ws + 10633216);          // 16.8 MB bf16 partials, over dead xb+wib
    u16*   wob      = (u16*)(ws + 35799040);          //  8 MB bf16 w_out

    fused_front<<<6410, 256, 0, stream>>>(x, wr, w_in, w_out,
                                          out + (size_t)T_TOK * D_DIM,
                                          top_e, top_g, xb, wib, wob,
                                          e0, blk_hist);
    prep_kernel<<<1, 1024, 0, stream>>>(top_e, ws_i, e0, e1, blk_hist);
    g1_a<<<640, 256, 0, stream>>>(xb, wib, ws_i, e0, e1, act);
    g2_a<<<640, 256, 0, stream>>>(act, wob, ws_i, e0, e1, top_g, y);
    combine_kernel<<<2048, 256, 0, stream>>>(y, out);
}